// Round 4
// baseline (374.917 us; speedup 1.0000x reference)
//
#include <hip/hip_runtime.h>
#include <math.h>

#define H 2048
#define R (4 * H)          // 8192 rows per weight matrix
#define L 3
#define NROWS_P1 (R + L * R)   // 32768 rows in phase 1

// Native clang vector type — __builtin_nontemporal_load requires this
// (HIP's float4 is a HIP_vector_type class and is rejected).
typedef float f4 __attribute__((ext_vector_type(4)));

// ---------------------------------------------------------------------------
// Wave-per-row GEMV. One 64-lane wave owns one row of the weight matrix:
// 8 coalesced float4 loads per lane (8 KB/wave from HBM), vector loads hit
// L1/L2. Reduce is a wave-private 6-step shuffle: no LDS, no __syncthreads.
// 4 independent waves per 256-thread block drift freely, so one wave's
// reduce tail overlaps another wave's loads. Dual accumulators halve the
// dependent-FMA chain so VALU latency doesn't gate load issue.
// ---------------------------------------------------------------------------

__device__ __forceinline__ float wave_row_dot(const float* __restrict__ row,
                                              const float* __restrict__ vec,
                                              int lane) {
    const f4* r4 = (const f4*)row;
    const f4* v4 = (const f4*)vec;
    float acc0 = 0.f, acc1 = 0.f;
#pragma unroll
    for (int it = 0; it < (H / 4) / 128; ++it) {   // 4 iterations of 2 chains
        const int i0 = (2 * it) * 64 + lane;
        const int i1 = (2 * it + 1) * 64 + lane;
        f4 a0 = __builtin_nontemporal_load(r4 + i0);  // weights: streamed once
        f4 a1 = __builtin_nontemporal_load(r4 + i1);
        f4 v0 = v4[i0];                               // vector: cache-resident
        f4 v1 = v4[i1];
        acc0 = fmaf(a0.x, v0.x, acc0);
        acc1 = fmaf(a1.x, v1.x, acc1);
        acc0 = fmaf(a0.y, v0.y, acc0);
        acc1 = fmaf(a1.y, v1.y, acc1);
        acc0 = fmaf(a0.z, v0.z, acc0);
        acc1 = fmaf(a1.z, v1.z, acc1);
        acc0 = fmaf(a0.w, v0.w, acc0);
        acc1 = fmaf(a1.w, v1.w, acc1);
    }
    float acc = acc0 + acc1;
#pragma unroll
    for (int off = 32; off > 0; off >>= 1)
        acc += __shfl_down(acc, off);
    return acc;   // lane 0 holds the row dot
}

// Phase 1: all input-independent GEMV rows in one launch (268 MB).
//   row g in [0, R):            xpart[g] = Wi[0][g,:] @ x
//   row g in [R, R + 3R):       pre[r]   = Wh[l][rr,:] @ h0[l] + bi[r] + bh[r]
//                               where r = g - R, l = r / R, rr = r % R
__global__ __launch_bounds__(256) void phase1_kernel(
    const float* __restrict__ Wi0,   // [R, H]
    const float* __restrict__ Wh,    // [L*R, H] flat
    const float* __restrict__ bi,    // [L*R]
    const float* __restrict__ bh,    // [L*R]
    const float* __restrict__ x,     // [H]
    const float* __restrict__ h0,    // [L, H]
    float* __restrict__ xpart,       // [R]
    float* __restrict__ pre)         // [L*R]
{
    const int wid  = threadIdx.x >> 6;
    const int lane = threadIdx.x & 63;
    const int g = blockIdx.x * 4 + wid;   // global row id in [0, 32768)

    const float* row;
    const float* vec;
    if (g < R) {
        row = Wi0 + (size_t)g * H;
        vec = x;
    } else {
        const int r = g - R;
        row = Wh + (size_t)r * H;
        vec = h0 + (r >> 13) * H;         // l = r / 8192
    }

    const float tot = wave_row_dot(row, vec, lane);

    if (lane == 0) {
        if (g < R) {
            xpart[g] = tot;
        } else {
            const int r = g - R;
            pre[r] = tot + bi[r] + bh[r];
        }
    }
}

// Phases 2/3: Wi[l] @ x_l  (no bias; bias already folded into pre[])
__global__ __launch_bounds__(256) void wix_kernel(
    const float* __restrict__ Wi,    // [R, H] this layer
    const float* __restrict__ x,     // [H]
    float* __restrict__ xpart)       // [R]
{
    const int wid  = threadIdx.x >> 6;
    const int lane = threadIdx.x & 63;
    const int g = blockIdx.x * 4 + wid;   // row in [0, R)
    const float tot = wave_row_dot(Wi + (size_t)g * H, x, lane);
    if (lane == 0) xpart[g] = tot;
}

// Elementwise LSTM cell update.
__global__ __launch_bounds__(256) void update_kernel(
    const float* __restrict__ pre_l,  // [R] Wh@h + biases, gate order i,f,g,o
    const float* __restrict__ xpart,  // [R] Wi@x
    const float* __restrict__ c0_l,   // [H]
    float* __restrict__ h_out)        // [H]
{
    const int j = blockIdx.x * blockDim.x + threadIdx.x;
    if (j >= H) return;

    const float gi = pre_l[j]         + xpart[j];
    const float gf = pre_l[H + j]     + xpart[H + j];
    const float gg = pre_l[2 * H + j] + xpart[2 * H + j];
    const float go = pre_l[3 * H + j] + xpart[3 * H + j];

    const float i_ = 1.f / (1.f + expf(-gi));
    const float f_ = 1.f / (1.f + expf(-gf));
    const float g_ = tanhf(gg);
    const float o_ = 1.f / (1.f + expf(-go));

    const float c_new = f_ * c0_l[j] + i_ * g_;
    h_out[j] = o_ * tanhf(c_new);
}

extern "C" void kernel_launch(void* const* d_in, const int* in_sizes, int n_in,
                              void* d_out, int out_size, void* d_ws, size_t ws_size,
                              hipStream_t stream) {
    const float* x    = (const float*)d_in[0];  // [H]
    const float* W_ih = (const float*)d_in[1];  // [L, R, H]
    const float* W_hh = (const float*)d_in[2];  // [L, R, H]
    const float* b_ih = (const float*)d_in[3];  // [L, R]
    const float* b_hh = (const float*)d_in[4];  // [L, R]
    const float* h0   = (const float*)d_in[5];  // [L, H]
    const float* c0   = (const float*)d_in[6];  // [L, H]
    float* out = (float*)d_out;                 // [H]

    float* xpart = (float*)d_ws;                // [R]
    float* pre   = xpart + R;                   // [L*R]
    float* xbuf1 = pre + L * R;                 // [H]
    float* xbuf2 = xbuf1 + H;                   // [H]

    const size_t Wstride = (size_t)R * H;

    // Phase 1: Wi[0]@x and all Wh[l]@h0[l] (+biases) — 268 MB, 4 rows/block.
    phase1_kernel<<<NROWS_P1 / 4, 256, 0, stream>>>(
        W_ih, W_hh, b_ih, b_hh, x, h0, xpart, pre);

    // Layer 0 update -> xbuf1
    update_kernel<<<H / 256, 256, 0, stream>>>(pre, xpart, c0, xbuf1);

    // Phase 2: Wi[1] @ xbuf1
    wix_kernel<<<R / 4, 256, 0, stream>>>(W_ih + Wstride, xbuf1, xpart);
    update_kernel<<<H / 256, 256, 0, stream>>>(pre + R, xpart, c0 + H, xbuf2);

    // Phase 3: Wi[2] @ xbuf2
    wix_kernel<<<R / 4, 256, 0, stream>>>(W_ih + 2 * Wstride, xbuf2, xpart);
    update_kernel<<<H / 256, 256, 0, stream>>>(pre + 2 * R, xpart, c0 + 2 * H, out);
}